// Round 2
// baseline (332.287 us; speedup 1.0000x reference)
//
#include <hip/hip_runtime.h>

// NeuralODE: y' = tanh(y@W1+b1)@W2+b2, fixed-step Dopri5, <=48 static iters.
// R5: barrier-free wave-autonomous design. Each WAVE owns 16 batch rows
// end-to-end and computes full 128-wide layers itself: 8 col-tiles x 4
// k-tiles = 32 MFMA per layer. Weights staged ONCE into LDS in
// B-frag-major layout (contiguous conflict-free ds_read_b128). The y->h->f
// transpose uses wave-PRIVATE LDS staging: no __syncthreads in the main
// loop, only s_waitcnt lgkmcnt(0) (same-wave LDS ops complete in order) +
// sched_barrier to pin compiler ordering. 128 thr/block (2 waves), grid 256
// -> 2 waves/CU, ~85KB LDS -> 1 block/CU. Serial critical path per f-eval
// drops from ~4600 cyc (8-wave barriers) to ~1500 cyc.

typedef __attribute__((ext_vector_type(8))) short short8;  // 8 bf16 = 4 VGPRs
typedef __attribute__((ext_vector_type(4))) float f32x4;

#define SL 136  // LDS row stride in bf16: 272B = 16B-aligned rows (b128 reads)

__device__ __forceinline__ short f2bf(float f) {
  union { float f; unsigned u; } v; v.f = f;
  return (short)((v.u + 0x8000u) >> 16);  // round-half-up, plenty for 0.1 budget
}

__device__ __forceinline__ float fast_tanh(float x) {
  // tanh(x) = 1 - 2/(e^{2x}+1); exact at +-inf, no branches.
  float e = __expf(2.0f * x);
  return 1.0f - __fdividef(2.0f, e + 1.0f);
}

__global__ __launch_bounds__(128, 1)
void node_kernel(const float* __restrict__ tptr, const float* __restrict__ x,
                 const float* __restrict__ W1, const float* __restrict__ b1,
                 const float* __restrict__ W2, const float* __restrict__ b2,
                 float* __restrict__ out) {
  const int tid  = threadIdx.x;
  const int wv   = tid >> 6;       // wave id within block (0..1)
  const int lane = tid & 63;
  const int q    = lane >> 4;      // quad within wave
  const int colL = lane & 15;      // col within 16-col tile / m row (A frag)
  const int blockRow = blockIdx.x * 32;
  const int waveRow  = blockRow + wv * 16;   // this wave's 16 rows

  // Frag-major weights: frag (ct,kt) is 512 bf16; lane reads 16B at
  // frag*1024B + lane*16B -> contiguous 1KB per read, conflict-free.
  __shared__ __align__(16) short WFs[2][32 * 512];   // 64 KB
  __shared__ __align__(16) short A1[2][16][SL];      // per-wave y staging
  __shared__ __align__(16) short A2[2][16][SL];      // per-wave h staging
  __shared__ float sred[128];
  __shared__ float srowY[128], srowH[128], srowF[128], srowY2[128], srowF2[128], sscale[128];

  short* const WF0 = &WFs[0][0];
  short* const WF1 = &WFs[1][0];

  // ---------- stage weights into frag-major LDS (one-time) ----------
  // B-frag 16x16x32: lane l holds W[k = kt*32 + (l>>4)*8 + j][n = ct*16 + (l&15)]
  for (int idx = tid; idx < 16384; idx += 128) {
    const int frag = idx >> 9;           // (ct*4 + kt)
    const int l = (idx >> 3) & 63, j = idx & 7;
    const int ct = frag >> 2, kt = frag & 3;
    const int k = kt * 32 + (l >> 4) * 8 + j;
    const int n = ct * 16 + (l & 15);
    WF0[idx] = f2bf(W1[k * 128 + n]);
    WF1[idx] = f2bf(W2[k * 128 + n]);
  }
  __syncthreads();

  // ---------- block-wide sum over 128 threads ----------
  auto block_sum = [&](float v) -> float {
    sred[tid] = v;
    __syncthreads();
    if (tid < 64) {
      float s = sred[tid] + sred[tid + 64];
#pragma unroll
      for (int o = 32; o > 0; o >>= 1) s += __shfl_down(s, o, 64);
      if (tid == 0) sred[0] = s;
    }
    __syncthreads();
    float r = sred[0];
    __syncthreads();
    return r;
  };

  // ---------- one MLP layer for a single row (fp32), thread = one col ----------
  auto mlp_row = [&](const float* vin, const float* __restrict__ Wg,
                     const float* __restrict__ bg, float* vout, bool dotanh) {
    float s = bg[tid];
#pragma unroll 8
    for (int k = 0; k < 128; ++k) s += vin[k] * Wg[k * 128 + tid];
    vout[tid] = dotanh ? fast_tanh(s) : s;
    __syncthreads();
  };

  // ---------- dt0: faithful port of initial_step_size (row 0, fp32) ----------
  srowY[tid] = x[tid];
  __syncthreads();
  mlp_row(srowY, W1, b1, srowH, true);
  mlp_row(srowH, W2, b2, srowF, false);
  {
    float sc = 1.4e-8f + fabsf(srowY[tid]) * 1.4e-8f;
    sscale[tid] = sc;
  }
  float a0 = srowY[tid] / sscale[tid];
  float a1 = srowF[tid] / sscale[tid];
  float d0 = sqrtf(block_sum(a0 * a0));
  float d1 = sqrtf(block_sum(a1 * a1));
  float h0 = (d0 < 1e-5f || d1 < 1e-5f) ? 1e-6f : 0.01f * d0 / d1;
  srowY2[tid] = srowY[tid] + h0 * srowF[tid];
  __syncthreads();
  mlp_row(srowY2, W1, b1, srowH, true);
  mlp_row(srowH, W2, b2, srowF2, false);
  float a2v = (srowF2[tid] - srowF[tid]) / sscale[tid];
  float d2 = sqrtf(block_sum(a2v * a2v)) / h0;
  float h1 = (d1 <= 1e-15f && d2 <= 1e-15f) ? fmaxf(1e-6f, h0 * 1e-3f)
                                            : powf(0.01f / (d1 + d2), 0.2f);
  const float dt0v = fminf(100.f * h0, h1);
  // (no further __syncthreads needed; waves are independent from here)

  // ---------- per-thread biases for each of its 8 col-tiles ----------
  float b1v[8], b2v[8];
#pragma unroll
  for (int ct = 0; ct < 8; ++ct) {
    b1v[ct] = b1[ct * 16 + colL];
    b2v[ct] = b2[ct * 16 + colL];
  }

  // ---------- load state y (C-layout: thread owns rows q*4+r, col ct*16+colL) ----------
  f32x4 yr[8];
#pragma unroll
  for (int ct = 0; ct < 8; ++ct)
#pragma unroll
    for (int r = 0; r < 4; ++r)
      yr[ct][r] = x[(waveRow + q * 4 + r) * 128 + ct * 16 + colL];

  // hoisted wave-private LDS addresses
  short* const wrA1 = &A1[wv][q * 4][colL];
  short* const wrA2 = &A2[wv][q * 4][colL];
  const short* const rdA1 = &A1[wv][colL][q * 8];
  const short* const rdA2 = &A2[wv][colL][q * 8];
  const short* const bf0 = WF0 + lane * 8;
  const short* const bf1 = WF1 + lane * 8;

  // ---------- one f-eval, fully wave-private (no barriers) ----------
  // gen(ct) produces the stage input for col-tile ct on the fly (saves VGPRs).
  auto evalF = [&](auto&& gen, f32x4 (&fout)[8]) {
#pragma unroll
    for (int ct = 0; ct < 8; ++ct) {
      f32x4 v = gen(ct);
#pragma unroll
      for (int r = 0; r < 4; ++r) wrA1[r * SL + ct * 16] = f2bf(v[r]);
    }
    // same-wave LDS ops complete in order: after this wait the writes are
    // visible to the cross-lane reads below. sched_barrier pins ordering.
    asm volatile("s_waitcnt lgkmcnt(0)" ::: "memory");
    __builtin_amdgcn_sched_barrier(0);
    short8 af[4];
#pragma unroll
    for (int kt = 0; kt < 4; ++kt) af[kt] = *(const short8*)(rdA1 + kt * 32);
    f32x4 acc[8];
#pragma unroll
    for (int ct = 0; ct < 8; ++ct) {
      acc[ct] = (f32x4){b1v[ct], b1v[ct], b1v[ct], b1v[ct]};
#pragma unroll
      for (int kt = 0; kt < 4; ++kt)
        acc[ct] = __builtin_amdgcn_mfma_f32_16x16x32_bf16(
            af[kt], *(const short8*)(bf0 + ((ct * 4 + kt) << 9)), acc[ct], 0, 0, 0);
    }
#pragma unroll
    for (int ct = 0; ct < 8; ++ct)
#pragma unroll
      for (int r = 0; r < 4; ++r)
        wrA2[r * SL + ct * 16] = f2bf(fast_tanh(acc[ct][r]));
    asm volatile("s_waitcnt lgkmcnt(0)" ::: "memory");
    __builtin_amdgcn_sched_barrier(0);
#pragma unroll
    for (int kt = 0; kt < 4; ++kt) af[kt] = *(const short8*)(rdA2 + kt * 32);
#pragma unroll
    for (int ct = 0; ct < 8; ++ct) {
      f32x4 a2 = (f32x4){b2v[ct], b2v[ct], b2v[ct], b2v[ct]};
#pragma unroll
      for (int kt = 0; kt < 4; ++kt)
        a2 = __builtin_amdgcn_mfma_f32_16x16x32_bf16(
            af[kt], *(const short8*)(bf1 + ((ct * 4 + kt) << 9)), a2, 0, 0, 0);
      fout[ct] = a2;
    }
  };

  // ---------- main fixed-step Dopri5 loop (wave-autonomous) ----------
  const float T = tptr[0] / 10.0f;  // t[0] / TIMESCALE
  float tt = 0.f;
  f32x4 k1[8], k2[8], k3[8], k4[8], k5[8], k6[8];

#pragma unroll 1
  for (int it = 0; it < 48; ++it) {
    float dt = fminf(fmaxf(T - tt, 0.f), dt0v);
    if (dt <= 0.f) break;  // uniform across threads and blocks; tt only grows
    evalF([&](int ct) { return yr[ct]; }, k1);
    {
      const float c1 = dt * 0.2f;
      evalF([&](int ct) { return yr[ct] + c1 * k1[ct]; }, k2);
    }
    {
      const float c1 = dt * 0.075f, c2 = dt * 0.225f;
      evalF([&](int ct) { return yr[ct] + c1 * k1[ct] + c2 * k2[ct]; }, k3);
    }
    {
      const float c1 = dt * 0.9777777777777777f, c2 = dt * -3.7333333333333334f,
                  c3 = dt * 3.5555555555555554f;
      evalF([&](int ct) { return yr[ct] + c1 * k1[ct] + c2 * k2[ct] + c3 * k3[ct]; }, k4);
    }
    {
      const float c1 = dt * 2.9525986892242035f, c2 = dt * -11.595793324188385f,
                  c3 = dt * 9.822892851699436f, c4 = dt * -0.2908093278463649f;
      evalF([&](int ct) {
        return yr[ct] + c1 * k1[ct] + c2 * k2[ct] + c3 * k3[ct] + c4 * k4[ct];
      }, k5);
    }
    {
      const float c1 = dt * 2.8462752525252526f, c2 = dt * -10.757575757575758f,
                  c3 = dt * 8.906422717743473f, c4 = dt * 0.2784090909090909f,
                  c5 = dt * -0.27351165254237287f;
      evalF([&](int ct) {
        return yr[ct] + c1 * k1[ct] + c2 * k2[ct] + c3 * k3[ct] + c4 * k4[ct]
                      + c5 * k5[ct];
      }, k6);
    }
    {
      const float c1 = dt * 0.0911458333333333f, c3 = dt * 0.449236298292902f,
                  c4 = dt * 0.6510416666666666f, c5 = dt * -0.32237617924528303f,
                  c6 = dt * 0.13095238095238096f;
#pragma unroll
      for (int ct = 0; ct < 8; ++ct)
        yr[ct] = yr[ct] + c1 * k1[ct] + c3 * k3[ct] + c4 * k4[ct] + c5 * k5[ct]
                        + c6 * k6[ct];
    }
    tt += dt;
  }

  // ---------- epilogue: out = stack([x, yT]) ----------
  {
    const float4* x4 = (const float4*)(x + blockRow * 128);
    float4* o4 = (float4*)(out + blockRow * 128);
#pragma unroll
    for (int i = tid; i < 1024; i += 128) o4[i] = x4[i];  // 32 rows * 128 f32
    float* oy = out + 8192 * 128;
#pragma unroll
    for (int ct = 0; ct < 8; ++ct)
#pragma unroll
      for (int r = 0; r < 4; ++r)
        oy[(waveRow + q * 4 + r) * 128 + ct * 16 + colL] = yr[ct][r];
  }
}

extern "C" void kernel_launch(void* const* d_in, const int* in_sizes, int n_in,
                              void* d_out, int out_size, void* d_ws, size_t ws_size,
                              hipStream_t stream) {
  const float* t  = (const float*)d_in[0];
  const float* x  = (const float*)d_in[1];
  const float* W1 = (const float*)d_in[2];
  const float* b1 = (const float*)d_in[3];
  const float* W2 = (const float*)d_in[4];
  const float* b2 = (const float*)d_in[5];
  float* out = (float*)d_out;
  node_kernel<<<dim3(256), dim3(128), 0, stream>>>(t, x, W1, b1, W2, b2, out);
}

// Round 3
// 164.040 us; speedup vs baseline: 2.0256x; 2.0256x over previous
//
#include <hip/hip_runtime.h>

// NeuralODE: y' = tanh(y@W1+b1)@W2+b2, fixed-step Dopri5, <=48 static iters.
// R6: R4's structure (weights as register B-frags, LDS round-trip transpose)
// but split into 256-thread blocks: 4 waves x 2 col-tiles, 16 rows/block,
// grid 512 -> 2 independent blocks/CU (8 waves/CU). Same per-wave work as R4
// (16 MFMA + 8 tanh per eval) but barriers sync 4 waves instead of 8, and the
// co-resident second block overlaps the first block's barrier/LDS stalls --
// the latency-hiding R4's monolithic 8-wave block could not get. R5's lesson
// applied: weights stay in VGPRs (64/wave), never re-read from LDS.

typedef __attribute__((ext_vector_type(8))) short short8;  // 8 bf16 = 4 VGPRs
typedef __attribute__((ext_vector_type(4))) float f32x4;

#define SL 136  // LDS row stride in bf16: 272B = 16B-aligned rows (b128 reads)

__device__ __forceinline__ short f2bf(float f) {
  union { float f; unsigned u; } v; v.f = f;
  return (short)((v.u + 0x8000u) >> 16);  // round-half-up, plenty for 0.1 budget
}

__device__ __forceinline__ float fast_tanh(float x) {
  // tanh(x) = 1 - 2/(e^{2x}+1); exact at +-inf, no branches.
  float e = __expf(2.0f * x);
  return 1.0f - __fdividef(2.0f, e + 1.0f);
}

__global__ __launch_bounds__(256, 2)
void node_kernel(const float* __restrict__ tptr, const float* __restrict__ x,
                 const float* __restrict__ W1, const float* __restrict__ b1,
                 const float* __restrict__ W2, const float* __restrict__ b2,
                 float* __restrict__ out) {
  const int tid  = threadIdx.x;
  const int wv   = tid >> 6;      // wave id (0..3); wave owns col-tiles 2wv,2wv+1
  const int lane = tid & 63;
  const int q    = lane >> 4;     // quad within wave
  const int colL = lane & 15;     // col within tile (C layout) / m row (A frag)
  const int blockRow = blockIdx.x * 16;

  __shared__ short A1[16][SL];   // staged y' (bf16, A-operand layout)
  __shared__ short A2[16][SL];   // staged tanh hidden (bf16)
  __shared__ float sred[256];
  __shared__ float spart[2][128];
  __shared__ float srowY[128], srowH[128], srowF[128], srowY2[128], srowF2[128], sscale[128];

  // ---------- weight B-fragments (bf16) + biases into registers ----------
  // B-frag 16x16x32: lane holds B[k = kt*32 + quad*8 + i][n], i=0..7.
  short8 w1f[2][4], w2f[2][4];
  float b1v[2], b2v[2];
  int ncol[2];
#pragma unroll
  for (int j = 0; j < 2; ++j) {
    const int n = (2 * wv + j) * 16 + colL;
    ncol[j] = n;
    b1v[j] = b1[n]; b2v[j] = b2[n];
#pragma unroll
    for (int kt = 0; kt < 4; ++kt) {
      short8 v1, v2;
#pragma unroll
      for (int i = 0; i < 8; ++i) {
        const int k = kt * 32 + q * 8 + i;
        v1[i] = f2bf(W1[k * 128 + n]);
        v2[i] = f2bf(W2[k * 128 + n]);
      }
      w1f[j][kt] = v1; w2f[j][kt] = v2;
    }
  }

  // ---------- block-wide sum (256 threads) ----------
  auto block_sum = [&](float v) -> float {
    sred[tid] = v;
    __syncthreads();
    if (tid < 64) {
      float s = sred[tid] + sred[tid + 64] + sred[tid + 128] + sred[tid + 192];
#pragma unroll
      for (int o = 32; o > 0; o >>= 1) s += __shfl_down(s, o, 64);
      if (tid == 0) sred[0] = s;
    }
    __syncthreads();
    float r = sred[0];
    __syncthreads();
    return r;
  };

  // ---------- one MLP layer for a single row (fp32, split-K over 256 thr) ----------
  auto mlp_layer = [&](const float* vin, const float* Wg, const float* bg,
                       float* vout, bool dotanh) {
    const int col = tid & 127, part = tid >> 7;  // 2 K-chunks of 64
    float s = 0.f;
    const float* wp = Wg + (part * 64) * 128 + col;
#pragma unroll 8
    for (int j = 0; j < 64; ++j) s += vin[part * 64 + j] * wp[j * 128];
    spart[part][col] = s;
    __syncthreads();
    if (tid < 128) {
      float a = bg[tid] + spart[0][tid] + spart[1][tid];
      vout[tid] = dotanh ? fast_tanh(a) : a;
    }
    __syncthreads();
  };

  // ---------- dt0: faithful port of initial_step_size (row 0, fp32) ----------
  if (tid < 128) srowY[tid] = x[tid];
  __syncthreads();
  mlp_layer(srowY, W1, b1, srowH, true);
  mlp_layer(srowH, W2, b2, srowF, false);
  float t0 = 0.f, t1 = 0.f;
  if (tid < 128) {
    float sc = 1.4e-8f + fabsf(srowY[tid]) * 1.4e-8f;
    sscale[tid] = sc;
    float a = srowY[tid] / sc; t0 = a * a;
    float bq = srowF[tid] / sc; t1 = bq * bq;
  }
  float d0 = sqrtf(block_sum(t0));
  float d1 = sqrtf(block_sum(t1));
  float h0 = (d0 < 1e-5f || d1 < 1e-5f) ? 1e-6f : 0.01f * d0 / d1;
  if (tid < 128) srowY2[tid] = srowY[tid] + h0 * srowF[tid];
  __syncthreads();
  mlp_layer(srowY2, W1, b1, srowH, true);
  mlp_layer(srowH, W2, b2, srowF2, false);
  float t2 = 0.f;
  if (tid < 128) { float a = (srowF2[tid] - srowF[tid]) / sscale[tid]; t2 = a * a; }
  float d2 = sqrtf(block_sum(t2)) / h0;
  float h1 = (d1 <= 1e-15f && d2 <= 1e-15f) ? fmaxf(1e-6f, h0 * 1e-3f)
                                            : powf(0.01f / (d1 + d2), 0.2f);
  const float dt0v = fminf(100.f * h0, h1);

  // ---------- load state y (C-layout: rows q*4+r, cols ncol[j]) ----------
  f32x4 yr[2];
#pragma unroll
  for (int j = 0; j < 2; ++j)
#pragma unroll
    for (int r = 0; r < 4; ++r)
      yr[j][r] = x[(blockRow + q * 4 + r) * 128 + ncol[j]];

  // hoisted LDS addresses (constant immediate offsets thereafter)
  short* const wr1 = &A1[q * 4][0];
  short* const wr2 = &A2[q * 4][0];
  const short* const rd1 = &A1[colL][q * 8];
  const short* const rd2 = &A2[colL][q * 8];

  // ---------- one f-eval: LDS round-trip transpose + 2 MFMA layers ----------
  auto evalF = [&](auto&& gen, f32x4 (&fout)[2]) {
#pragma unroll
    for (int j = 0; j < 2; ++j) {
      f32x4 v = gen(j);
#pragma unroll
      for (int r = 0; r < 4; ++r) wr1[r * SL + ncol[j]] = f2bf(v[r]);
    }
    __syncthreads();
    short8 af[4];
#pragma unroll
    for (int kt = 0; kt < 4; ++kt) af[kt] = *(const short8*)(rd1 + kt * 32);
    f32x4 acc0 = {b1v[0], b1v[0], b1v[0], b1v[0]};
    f32x4 acc1 = {b1v[1], b1v[1], b1v[1], b1v[1]};
    __builtin_amdgcn_s_setprio(1);
#pragma unroll
    for (int kt = 0; kt < 4; ++kt) {
      acc0 = __builtin_amdgcn_mfma_f32_16x16x32_bf16(af[kt], w1f[0][kt], acc0, 0, 0, 0);
      acc1 = __builtin_amdgcn_mfma_f32_16x16x32_bf16(af[kt], w1f[1][kt], acc1, 0, 0, 0);
    }
    __builtin_amdgcn_s_setprio(0);
#pragma unroll
    for (int r = 0; r < 4; ++r) wr2[r * SL + ncol[0]] = f2bf(fast_tanh(acc0[r]));
#pragma unroll
    for (int r = 0; r < 4; ++r) wr2[r * SL + ncol[1]] = f2bf(fast_tanh(acc1[r]));
    __syncthreads();
#pragma unroll
    for (int kt = 0; kt < 4; ++kt) af[kt] = *(const short8*)(rd2 + kt * 32);
    f32x4 f0 = {b2v[0], b2v[0], b2v[0], b2v[0]};
    f32x4 f1 = {b2v[1], b2v[1], b2v[1], b2v[1]};
    __builtin_amdgcn_s_setprio(1);
#pragma unroll
    for (int kt = 0; kt < 4; ++kt) {
      f0 = __builtin_amdgcn_mfma_f32_16x16x32_bf16(af[kt], w2f[0][kt], f0, 0, 0, 0);
      f1 = __builtin_amdgcn_mfma_f32_16x16x32_bf16(af[kt], w2f[1][kt], f1, 0, 0, 0);
    }
    __builtin_amdgcn_s_setprio(0);
    fout[0] = f0; fout[1] = f1;
  };

  // ---------- main fixed-step Dopri5 loop ----------
  const float T = tptr[0] / 10.0f;  // t[0] / TIMESCALE
  float tt = 0.f;
  f32x4 k1[2], k2[2], k3[2], k4[2], k5[2], k6[2];

#pragma unroll 1
  for (int it = 0; it < 48; ++it) {
    float dt = fminf(fmaxf(T - tt, 0.f), dt0v);
    if (dt <= 0.f) break;  // uniform across threads and blocks; tt only grows
    evalF([&](int j) { return yr[j]; }, k1);
    {
      const float c1 = dt * 0.2f;
      evalF([&](int j) { return yr[j] + c1 * k1[j]; }, k2);
    }
    {
      const float c1 = dt * 0.075f, c2 = dt * 0.225f;
      evalF([&](int j) { return yr[j] + c1 * k1[j] + c2 * k2[j]; }, k3);
    }
    {
      const float c1 = dt * 0.9777777777777777f, c2 = dt * -3.7333333333333334f,
                  c3 = dt * 3.5555555555555554f;
      evalF([&](int j) { return yr[j] + c1 * k1[j] + c2 * k2[j] + c3 * k3[j]; }, k4);
    }
    {
      const float c1 = dt * 2.9525986892242035f, c2 = dt * -11.595793324188385f,
                  c3 = dt * 9.822892851699436f, c4 = dt * -0.2908093278463649f;
      evalF([&](int j) {
        return yr[j] + c1 * k1[j] + c2 * k2[j] + c3 * k3[j] + c4 * k4[j];
      }, k5);
    }
    {
      const float c1 = dt * 2.8462752525252526f, c2 = dt * -10.757575757575758f,
                  c3 = dt * 8.906422717743473f, c4 = dt * 0.2784090909090909f,
                  c5 = dt * -0.27351165254237287f;
      evalF([&](int j) {
        return yr[j] + c1 * k1[j] + c2 * k2[j] + c3 * k3[j] + c4 * k4[j]
                     + c5 * k5[j];
      }, k6);
    }
    {
      const float c1 = dt * 0.0911458333333333f, c3 = dt * 0.449236298292902f,
                  c4 = dt * 0.6510416666666666f, c5 = dt * -0.32237617924528303f,
                  c6 = dt * 0.13095238095238096f;
#pragma unroll
      for (int j = 0; j < 2; ++j)
        yr[j] = yr[j] + c1 * k1[j] + c3 * k3[j] + c4 * k4[j] + c5 * k5[j]
                      + c6 * k6[j];
    }
    tt += dt;
  }

  // ---------- epilogue: out = stack([x, yT]) ----------
  {
    const float4* x4 = (const float4*)(x + blockRow * 128);
    float4* o4 = (float4*)(out + blockRow * 128);
    o4[tid] = x4[tid];              // 16 rows * 128 f32 = 512 float4
    o4[tid + 256] = x4[tid + 256];
    float* oy = out + 8192 * 128;
#pragma unroll
    for (int j = 0; j < 2; ++j)
#pragma unroll
      for (int r = 0; r < 4; ++r)
        oy[(blockRow + q * 4 + r) * 128 + ncol[j]] = yr[j][r];
  }
}

extern "C" void kernel_launch(void* const* d_in, const int* in_sizes, int n_in,
                              void* d_out, int out_size, void* d_ws, size_t ws_size,
                              hipStream_t stream) {
  const float* t  = (const float*)d_in[0];
  const float* x  = (const float*)d_in[1];
  const float* W1 = (const float*)d_in[2];
  const float* b1 = (const float*)d_in[3];
  const float* W2 = (const float*)d_in[4];
  const float* b2 = (const float*)d_in[5];
  float* out = (float*)d_out;
  node_kernel<<<dim3(512), dim3(256), 0, stream>>>(t, x, W1, b1, W2, b2, out);
}

// Round 5
// 138.368 us; speedup vs baseline: 2.4015x; 1.1855x over previous
//
#include <hip/hip_runtime.h>

// NeuralODE: y' = tanh(y@W1+b1)@W2+b2, fixed-step Dopri5, <=48 static iters.
// R7b: R6 shape (4 waves x 2 col-tiles, 16 rows/block, grid 512 -> 2 blocks/CU,
// weights as register B-frags, LDS round-trip transpose, 2 barriers/eval).
// VALU-trim round: (a) staging via v_cvt_pk_bf16_f32 (1 instr / 2 values) with
// lo/hi b16 stores (d16_hi fold) instead of 16x add+shift; (b) tanh in 5 ops
// (exp2 with folded 2*log2e constant, rcp, inline-const fma); (c) dt0 prologue
// reuses the MFMA evalF on row-0-broadcast state instead of 4 serial 64-deep
// fp32 MLPs (saves ~4us + 3KB LDS; dt0 shifts ~0.3% from bf16 weights, well
// within output tolerance). [R7 fix: __builtin_amdgcn_exp2f, not _expf]

typedef __attribute__((ext_vector_type(8))) short short8;  // 8 bf16 = 4 VGPRs
typedef __attribute__((ext_vector_type(4))) float f32x4;

#define SL 136  // LDS row stride in bf16: 272B = 16B-aligned rows (b128 reads)

__device__ __forceinline__ short f2bf(float f) {
  union { float f; unsigned u; } v; v.f = f;
  return (short)((v.u + 0x8000u) >> 16);  // for weight load only (not hot)
}

__device__ __forceinline__ float fast_tanh(float x) {
  // tanh(x) = 1 - 2/(exp2(c*x)+1), c = 2*log2(e). 5 VALU ops, exact at +-inf.
  float e = __builtin_amdgcn_exp2f(x * 2.88539008177793f);
  float r = __builtin_amdgcn_rcpf(e + 1.0f);
  return __builtin_fmaf(-2.0f, r, 1.0f);
}

// pack 2 f32 -> 2 bf16 in one instr; store lo/hi halves to two LDS addrs
// (compiler folds the hi store to ds_write_b16_d16_hi).
__device__ __forceinline__ void store_bf16_pair(short* p0, short* p1,
                                                float a, float b) {
  unsigned u;
  asm("v_cvt_pk_bf16_f32 %0, %1, %2" : "=v"(u) : "v"(a), "v"(b));
  *p0 = (short)(u & 0xffffu);
  *p1 = (short)(u >> 16);
}

__global__ __launch_bounds__(256, 2)
void node_kernel(const float* __restrict__ tptr, const float* __restrict__ x,
                 const float* __restrict__ W1, const float* __restrict__ b1,
                 const float* __restrict__ W2, const float* __restrict__ b2,
                 float* __restrict__ out) {
  const int tid  = threadIdx.x;
  const int wv   = tid >> 6;      // wave id (0..3); wave owns col-tiles 2wv,2wv+1
  const int lane = tid & 63;
  const int q    = lane >> 4;     // quad within wave
  const int colL = lane & 15;     // col within tile (C layout) / m row (A frag)
  const int blockRow = blockIdx.x * 16;

  __shared__ short A1[16][SL];   // staged y' (bf16, A-operand layout)
  __shared__ short A2[16][SL];   // staged tanh hidden (bf16)
  __shared__ float sred[256];

  // ---------- weight B-fragments (bf16) + biases into registers ----------
  // B-frag 16x16x32: lane holds B[k = kt*32 + quad*8 + i][n], i=0..7.
  short8 w1f[2][4], w2f[2][4];
  float b1v[2], b2v[2];
  int ncol[2];
#pragma unroll
  for (int j = 0; j < 2; ++j) {
    const int n = (2 * wv + j) * 16 + colL;
    ncol[j] = n;
    b1v[j] = b1[n]; b2v[j] = b2[n];
#pragma unroll
    for (int kt = 0; kt < 4; ++kt) {
      short8 v1, v2;
#pragma unroll
      for (int i = 0; i < 8; ++i) {
        const int k = kt * 32 + q * 8 + i;
        v1[i] = f2bf(W1[k * 128 + n]);
        v2[i] = f2bf(W2[k * 128 + n]);
      }
      w1f[j][kt] = v1; w2f[j][kt] = v2;
    }
  }

  // ---------- block-wide sum (256 threads) ----------
  auto block_sum = [&](float v) -> float {
    sred[tid] = v;
    __syncthreads();
    if (tid < 64) {
      float s = sred[tid] + sred[tid + 64] + sred[tid + 128] + sred[tid + 192];
#pragma unroll
      for (int o = 32; o > 0; o >>= 1) s += __shfl_down(s, o, 64);
      if (tid == 0) sred[0] = s;
    }
    __syncthreads();
    float r = sred[0];
    __syncthreads();
    return r;
  };

  // hoisted LDS addresses (constant immediate offsets thereafter)
  short* const wr1 = &A1[q * 4][0];
  short* const wr2 = &A2[q * 4][0];
  const short* const rd1 = &A1[colL][q * 8];
  const short* const rd2 = &A2[colL][q * 8];

  // ---------- one f-eval: LDS round-trip transpose + 2 MFMA layers ----------
  auto evalF = [&](auto&& gen, f32x4 (&fout)[2]) {
#pragma unroll
    for (int j = 0; j < 2; ++j) {
      f32x4 v = gen(j);
      store_bf16_pair(&wr1[0 * SL + ncol[j]], &wr1[1 * SL + ncol[j]], v[0], v[1]);
      store_bf16_pair(&wr1[2 * SL + ncol[j]], &wr1[3 * SL + ncol[j]], v[2], v[3]);
    }
    __syncthreads();
    short8 af[4];
#pragma unroll
    for (int kt = 0; kt < 4; ++kt) af[kt] = *(const short8*)(rd1 + kt * 32);
    f32x4 acc0 = {b1v[0], b1v[0], b1v[0], b1v[0]};
    f32x4 acc1 = {b1v[1], b1v[1], b1v[1], b1v[1]};
    __builtin_amdgcn_s_setprio(1);
#pragma unroll
    for (int kt = 0; kt < 4; ++kt) {
      acc0 = __builtin_amdgcn_mfma_f32_16x16x32_bf16(af[kt], w1f[0][kt], acc0, 0, 0, 0);
      acc1 = __builtin_amdgcn_mfma_f32_16x16x32_bf16(af[kt], w1f[1][kt], acc1, 0, 0, 0);
    }
    __builtin_amdgcn_s_setprio(0);
    {
      float h0a = fast_tanh(acc0[0]), h1a = fast_tanh(acc0[1]);
      float h2a = fast_tanh(acc0[2]), h3a = fast_tanh(acc0[3]);
      store_bf16_pair(&wr2[0 * SL + ncol[0]], &wr2[1 * SL + ncol[0]], h0a, h1a);
      store_bf16_pair(&wr2[2 * SL + ncol[0]], &wr2[3 * SL + ncol[0]], h2a, h3a);
      float h0b = fast_tanh(acc1[0]), h1b = fast_tanh(acc1[1]);
      float h2b = fast_tanh(acc1[2]), h3b = fast_tanh(acc1[3]);
      store_bf16_pair(&wr2[0 * SL + ncol[1]], &wr2[1 * SL + ncol[1]], h0b, h1b);
      store_bf16_pair(&wr2[2 * SL + ncol[1]], &wr2[3 * SL + ncol[1]], h2b, h3b);
    }
    __syncthreads();
#pragma unroll
    for (int kt = 0; kt < 4; ++kt) af[kt] = *(const short8*)(rd2 + kt * 32);
    f32x4 f0 = {b2v[0], b2v[0], b2v[0], b2v[0]};
    f32x4 f1 = {b2v[1], b2v[1], b2v[1], b2v[1]};
    __builtin_amdgcn_s_setprio(1);
#pragma unroll
    for (int kt = 0; kt < 4; ++kt) {
      f0 = __builtin_amdgcn_mfma_f32_16x16x32_bf16(af[kt], w2f[0][kt], f0, 0, 0, 0);
      f1 = __builtin_amdgcn_mfma_f32_16x16x32_bf16(af[kt], w2f[1][kt], f1, 0, 0, 0);
    }
    __builtin_amdgcn_s_setprio(0);
    fout[0] = f0; fout[1] = f1;
  };

  // ---------- dt0 via the MFMA evalF on row-0-broadcast state ----------
  // Each thread loads y0 at its two cols; evalF on the broadcast state gives
  // f(y0) in every row. Norm sums take q==0 threads only (each col once).
  float y0j[2], scl[2];
#pragma unroll
  for (int j = 0; j < 2; ++j) {
    y0j[j] = x[ncol[j]];
    scl[j] = 1.4e-8f + fabsf(y0j[j]) * 1.4e-8f;
  }
  f32x4 fb[2];
  evalF([&](int j) { float v = y0j[j]; return (f32x4){v, v, v, v}; }, fb);
  float f0j[2] = {fb[0][0], fb[1][0]};
  float t0 = 0.f, t1 = 0.f;
  if (q == 0) {
#pragma unroll
    for (int j = 0; j < 2; ++j) {
      float a = y0j[j] / scl[j]; t0 += a * a;
      float b = f0j[j] / scl[j]; t1 += b * b;
    }
  }
  float d0 = sqrtf(block_sum(t0));
  float d1 = sqrtf(block_sum(t1));
  float h0 = (d0 < 1e-5f || d1 < 1e-5f) ? 1e-6f : 0.01f * d0 / d1;
  evalF([&](int j) { float v = y0j[j] + h0 * f0j[j]; return (f32x4){v, v, v, v}; }, fb);
  float t2 = 0.f;
  if (q == 0) {
#pragma unroll
    for (int j = 0; j < 2; ++j) {
      float a = (fb[j][0] - f0j[j]) / scl[j]; t2 += a * a;
    }
  }
  float d2 = sqrtf(block_sum(t2)) / h0;
  float h1 = (d1 <= 1e-15f && d2 <= 1e-15f) ? fmaxf(1e-6f, h0 * 1e-3f)
                                            : powf(0.01f / (d1 + d2), 0.2f);
  const float dt0v = fminf(100.f * h0, h1);

  // ---------- load state y (C-layout: rows q*4+r, cols ncol[j]) ----------
  f32x4 yr[2];
#pragma unroll
  for (int j = 0; j < 2; ++j)
#pragma unroll
    for (int r = 0; r < 4; ++r)
      yr[j][r] = x[(blockRow + q * 4 + r) * 128 + ncol[j]];

  // ---------- main fixed-step Dopri5 loop ----------
  const float T = tptr[0] / 10.0f;  // t[0] / TIMESCALE
  float tt = 0.f;
  f32x4 k1[2], k2[2], k3[2], k4[2], k5[2], k6[2];

#pragma unroll 1
  for (int it = 0; it < 48; ++it) {
    float dt = fminf(fmaxf(T - tt, 0.f), dt0v);
    if (dt <= 0.f) break;  // uniform across threads and blocks; tt only grows
    evalF([&](int j) { return yr[j]; }, k1);
    {
      const float c1 = dt * 0.2f;
      evalF([&](int j) { return yr[j] + c1 * k1[j]; }, k2);
    }
    {
      const float c1 = dt * 0.075f, c2 = dt * 0.225f;
      evalF([&](int j) { return yr[j] + c1 * k1[j] + c2 * k2[j]; }, k3);
    }
    {
      const float c1 = dt * 0.9777777777777777f, c2 = dt * -3.7333333333333334f,
                  c3 = dt * 3.5555555555555554f;
      evalF([&](int j) { return yr[j] + c1 * k1[j] + c2 * k2[j] + c3 * k3[j]; }, k4);
    }
    {
      const float c1 = dt * 2.9525986892242035f, c2 = dt * -11.595793324188385f,
                  c3 = dt * 9.822892851699436f, c4 = dt * -0.2908093278463649f;
      evalF([&](int j) {
        return yr[j] + c1 * k1[j] + c2 * k2[j] + c3 * k3[j] + c4 * k4[j];
      }, k5);
    }
    {
      const float c1 = dt * 2.8462752525252526f, c2 = dt * -10.757575757575758f,
                  c3 = dt * 8.906422717743473f, c4 = dt * 0.2784090909090909f,
                  c5 = dt * -0.27351165254237287f;
      evalF([&](int j) {
        return yr[j] + c1 * k1[j] + c2 * k2[j] + c3 * k3[j] + c4 * k4[j]
                     + c5 * k5[j];
      }, k6);
    }
    {
      const float c1 = dt * 0.0911458333333333f, c3 = dt * 0.449236298292902f,
                  c4 = dt * 0.6510416666666666f, c5 = dt * -0.32237617924528303f,
                  c6 = dt * 0.13095238095238096f;
#pragma unroll
      for (int j = 0; j < 2; ++j)
        yr[j] = yr[j] + c1 * k1[j] + c3 * k3[j] + c4 * k4[j] + c5 * k5[j]
                      + c6 * k6[j];
    }
    tt += dt;
  }

  // ---------- epilogue: out = stack([x, yT]) ----------
  {
    const float4* x4 = (const float4*)(x + blockRow * 128);
    float4* o4 = (float4*)(out + blockRow * 128);
    o4[tid] = x4[tid];              // 16 rows * 128 f32 = 512 float4
    o4[tid + 256] = x4[tid + 256];
    float* oy = out + 8192 * 128;
#pragma unroll
    for (int j = 0; j < 2; ++j)
#pragma unroll
      for (int r = 0; r < 4; ++r)
        oy[(blockRow + q * 4 + r) * 128 + ncol[j]] = yr[j][r];
  }
}

extern "C" void kernel_launch(void* const* d_in, const int* in_sizes, int n_in,
                              void* d_out, int out_size, void* d_ws, size_t ws_size,
                              hipStream_t stream) {
  const float* t  = (const float*)d_in[0];
  const float* x  = (const float*)d_in[1];
  const float* W1 = (const float*)d_in[2];
  const float* b1 = (const float*)d_in[3];
  const float* W2 = (const float*)d_in[4];
  const float* b2 = (const float*)d_in[5];
  float* out = (float*)d_out;
  node_kernel<<<dim3(512), dim3(256), 0, stream>>>(t, x, W1, b1, W2, b2, out);
}